// Round 9
// baseline (631.267 us; speedup 1.0000x reference)
//
#include <hip/hip_runtime.h>

#define HDIM 64

__device__ __forceinline__ float fast_sigmoid(float v) {
    return __builtin_amdgcn_rcpf(1.0f + __builtin_amdgcn_exp2f(-1.442695041f * v));
}

__device__ __forceinline__ float fast_tanh(float v) {
    return 1.0f - 2.0f * __builtin_amdgcn_rcpf(1.0f + __builtin_amdgcn_exp2f(2.885390082f * v));
}

// Butterfly add across lane^16 / lane^32 on the VALU (no DS pipe).
#if defined(__has_builtin)
# if __has_builtin(__builtin_amdgcn_permlane16_swap) && __has_builtin(__builtin_amdgcn_permlane32_swap)
#  define HAVE_PERMLANE_SWAP 1
# endif
#endif

#ifdef HAVE_PERMLANE_SWAP
typedef unsigned uv2 __attribute__((ext_vector_type(2)));
__device__ __forceinline__ float bfly_add16(float v) {
    uv2 r = __builtin_amdgcn_permlane16_swap(__float_as_uint(v), __float_as_uint(v), false, false);
    return __uint_as_float(r[0]) + __uint_as_float(r[1]);
}
__device__ __forceinline__ float bfly_add32(float v) {
    uv2 r = __builtin_amdgcn_permlane32_swap(__float_as_uint(v), __float_as_uint(v), false, false);
    return __uint_as_float(r[0]) + __uint_as_float(r[1]);
}
#else
__device__ __forceinline__ float bfly_add16(float v) { return v + __shfl_xor(v, 16); }
__device__ __forceinline__ float bfly_add32(float v) { return v + __shfl_xor(v, 32); }
#endif

// 256 threads = 4 waves; block handles TWO batch elements (2b, 2b+1).
// lane l of wave w:  j = l>>4 (k-slice group), i = l&15, output m = w*16+i.
// Lane holds weights for ALL 4 gates of output m over k in [16j,16j+16):
//   64 floats pinned in VGPRs (weights shared by both batch elements).
// Two independent dot/cell chains per thread per step fill each other's
// latency shadow (the r6 kernel was serial-latency-bound, not pipe-bound).
// x staged through LDS per 64-step chunk, interleaved [s][elem][comp].
__global__ __launch_bounds__(256)
__attribute__((amdgpu_waves_per_eu(2, 2)))
void bilstm_kernel(const float* __restrict__ x,
                   const float* __restrict__ w_ih_f,
                   const float* __restrict__ w_hh_f,
                   const float* __restrict__ b_ih_f,
                   const float* __restrict__ b_hh_f,
                   const float* __restrict__ w_ih_b,
                   const float* __restrict__ b_ih_b,
                   const float* __restrict__ b_hh_b,
                   const float* __restrict__ w_fc,
                   const float* __restrict__ b_fc,
                   float* __restrict__ out,
                   int T)
{
    const int b   = blockIdx.x;      // handles batch 2b and 2b+1
    const int tid = threadIdx.x;
    const int w   = tid >> 6;        // wave 0..3
    const int l   = tid & 63;        // lane 0..63
    const int j   = l >> 4;          // k-slice group 0..3
    const int i   = l & 15;
    const int m   = (w << 4) | i;    // output index 0..63

    __shared__ float hbuf[2][2][HDIM];   // [parity][elem][64]
    __shared__ float xstage[2][512];     // [parity][s*8 + elem*4 + comp]

    // ---- per-lane weights: 4 gates x k-slice [16j,16j+16) ----
    float4 wv[4][4];
    float  wx[4], bz[4];
    #pragma unroll
    for (int g = 0; g < 4; ++g) {
        const int r = (g << 6) | m;
        const float* row = w_hh_f + (size_t)r * HDIM + (j << 4);
        #pragma unroll
        for (int q = 0; q < 4; ++q) wv[g][q] = ((const float4*)row)[q];
        wx[g] = w_ih_f[(size_t)r * 4 + j];                  // x-weight, component j
        bz[g] = (j == 0) ? (b_ih_f[r] + b_hh_f[r]) : 0.0f;  // bias seeded once
    }
    #pragma unroll
    for (int g = 0; g < 4; ++g) {
        #pragma unroll
        for (int q = 0; q < 4; ++q)
            asm volatile("" : "+v"(wv[g][q].x), "+v"(wv[g][q].y),
                              "+v"(wv[g][q].z), "+v"(wv[g][q].w));
    }
    asm volatile("" : "+v"(wx[0]), "+v"(wx[1]), "+v"(wx[2]), "+v"(wx[3]));
    asm volatile("" : "+v"(bz[0]), "+v"(bz[1]), "+v"(bz[2]), "+v"(bz[3]));

    const float* xb0 = x + (size_t)(2 * b)     * T * 4;
    const float* xb1 = x + (size_t)(2 * b + 1) * T * 4;
    const int lim = T * 4 - 1;
    const int sslot = ((tid >> 2) << 3) | (tid & 3);   // s*8 + comp

    // prologue: stage chunk 0, zero h
    {
        int idx = tid;  if (idx > lim) idx = lim;
        xstage[0][sslot]     = xb0[idx];
        xstage[0][sslot + 4] = xb1[idx];
    }
    if (tid < 2 * HDIM) hbuf[0][tid >> 6][tid & 63] = 0.0f;
    __syncthreads();

    float c0 = 0.0f, h0 = 0.0f, c1 = 0.0f, h1 = 0.0f;
    const int NCH = (T + 63) >> 6;   // chunks of 64 timesteps

    for (int ch = 0; ch < NCH; ++ch) {
        const int nst = ((T - (ch << 6)) < 64) ? (T - (ch << 6)) : 64;
        const float* xs = xstage[ch & 1];
        const bool more = (ch + 1 < NCH);
        float xn0 = 0.0f, xn1 = 0.0f;
        if (more) {
            int idx = ((ch + 1) << 8) + tid;  if (idx > lim) idx = lim;
            xn0 = xb0[idx];
            xn1 = xb1[idx];
        }

        // accumulate one h-quad into elem-E accumulators
        #define ACC4(E, HV, Q, A0, A1, A2, A3)                              \
            A0##E += wv[0][Q].x * HV.x; A0##E += wv[0][Q].y * HV.y;         \
            A0##E += wv[0][Q].z * HV.z; A0##E += wv[0][Q].w * HV.w;         \
            A1##E += wv[1][Q].x * HV.x; A1##E += wv[1][Q].y * HV.y;         \
            A1##E += wv[1][Q].z * HV.z; A1##E += wv[1][Q].w * HV.w;         \
            A2##E += wv[2][Q].x * HV.x; A2##E += wv[2][Q].y * HV.y;         \
            A2##E += wv[2][Q].z * HV.z; A2##E += wv[2][Q].w * HV.w;         \
            A3##E += wv[3][Q].x * HV.x; A3##E += wv[3][Q].y * HV.y;         \
            A3##E += wv[3][Q].z * HV.z; A3##E += wv[3][Q].w * HV.w;

        #define STEP(S, RA, RB) do {                                        \
            const float xj0 = xs[((S) << 3) + j];                           \
            const float xj1 = xs[((S) << 3) + 4 + j];                       \
            const float4* hp0 = (const float4*)(&hbuf[RA][0][j << 4]);      \
            const float4* hp1 = (const float4*)(&hbuf[RA][1][j << 4]);      \
            float4 ha0 = hp0[0], ha1 = hp0[1], ha2 = hp0[2], ha3 = hp0[3];  \
            float4 hb0 = hp1[0], hb1 = hp1[1], hb2 = hp1[2], hb3 = hp1[3];  \
            float p0a = bz[0] + wx[0] * xj0, p1a = bz[1] + wx[1] * xj0;     \
            float p2a = bz[2] + wx[2] * xj0, p3a = bz[3] + wx[3] * xj0;     \
            float q0a = 0.0f, q1a = 0.0f, q2a = 0.0f, q3a = 0.0f;           \
            float p0b = bz[0] + wx[0] * xj1, p1b = bz[1] + wx[1] * xj1;     \
            float p2b = bz[2] + wx[2] * xj1, p3b = bz[3] + wx[3] * xj1;     \
            float q0b = 0.0f, q1b = 0.0f, q2b = 0.0f, q3b = 0.0f;           \
            ACC4(a, ha0, 0, p0, p1, p2, p3)                                 \
            ACC4(b, hb0, 0, p0, p1, p2, p3)                                 \
            ACC4(a, ha1, 1, q0, q1, q2, q3)                                 \
            ACC4(b, hb1, 1, q0, q1, q2, q3)                                 \
            ACC4(a, ha2, 2, p0, p1, p2, p3)                                 \
            ACC4(b, hb2, 2, p0, p1, p2, p3)                                 \
            ACC4(a, ha3, 3, q0, q1, q2, q3)                                 \
            ACC4(b, hb3, 3, q0, q1, q2, q3)                                 \
            p0a += q0a; p1a += q1a; p2a += q2a; p3a += q3a;                 \
            p0b += q0b; p1b += q1b; p2b += q2b; p3b += q3b;                 \
            p0a = bfly_add16(p0a); p1a = bfly_add16(p1a);                   \
            p2a = bfly_add16(p2a); p3a = bfly_add16(p3a);                   \
            p0b = bfly_add16(p0b); p1b = bfly_add16(p1b);                   \
            p2b = bfly_add16(p2b); p3b = bfly_add16(p3b);                   \
            p0a = bfly_add32(p0a); p1a = bfly_add32(p1a);                   \
            p2a = bfly_add32(p2a); p3a = bfly_add32(p3a);                   \
            p0b = bfly_add32(p0b); p1b = bfly_add32(p1b);                   \
            p2b = bfly_add32(p2b); p3b = bfly_add32(p3b);                   \
            const float gia = fast_sigmoid(p0a), gib = fast_sigmoid(p0b);   \
            const float gfa = fast_sigmoid(p1a), gfb = fast_sigmoid(p1b);   \
            const float gga = fast_tanh(p2a),   ggb = fast_tanh(p2b);       \
            const float goa = fast_sigmoid(p3a), gob = fast_sigmoid(p3b);   \
            c0 = gfa * c0 + gia * gga;                                      \
            c1 = gfb * c1 + gib * ggb;                                      \
            h0 = goa * fast_tanh(c0);                                       \
            h1 = gob * fast_tanh(c1);                                       \
            if (j < 2) hbuf[RB][j][m] = j ? h1 : h0;                        \
            __syncthreads();                                                \
        } while (0)

        for (int s = 0; s < nst; s += 2) {
            STEP(s,     0, 1);
            STEP(s + 1, 1, 0);
        }
        #undef STEP
        #undef ACC4

        if (more) {
            xstage[(ch + 1) & 1][sslot]     = xn0;
            xstage[(ch + 1) & 1][sslot + 4] = xn1;
            __syncthreads();
        }
    }

    // ---- epilogue: wave w (0,1) handles batch elem w: backward cell + fc ----
    if (w < 2) {
        const float* xbw = w ? xb1 : xb0;
        float4 xl = *(const float4*)(xbw + 4 * (T - 1));
        float gb[4];
        #pragma unroll
        for (int jj = 0; jj < 4; ++jj) {
            const int rr2 = (jj << 6) | l;
            float4 wb = *(const float4*)(w_ih_b + (size_t)rr2 * 4);
            gb[jj] = b_ih_b[rr2] + b_hh_b[rr2]
                   + wb.x * xl.x + wb.y * xl.y + wb.z * xl.z + wb.w * xl.w;
        }
        const float ib  = fast_sigmoid(gb[0]);
        const float ggv = fast_tanh(gb[2]);
        const float ob  = fast_sigmoid(gb[3]);
        const float cb  = ib * ggv;
        const float hbk = ob * fast_tanh(cb);

        const float hf = hbuf[0][w][l];   // T even -> final h in parity 0
        float p = w_fc[l] * hf + w_fc[HDIM + l] * hbk;
        #pragma unroll
        for (int off = 32; off; off >>= 1) p += __shfl_xor(p, off);

        if (l == 0) out[2 * b + w] = fast_sigmoid(p + b_fc[0]);
    }
}

extern "C" void kernel_launch(void* const* d_in, const int* in_sizes, int n_in,
                              void* d_out, int out_size, void* d_ws, size_t ws_size,
                              hipStream_t stream) {
    const float* x      = (const float*)d_in[0];
    const float* w_ih_f = (const float*)d_in[1];
    const float* w_hh_f = (const float*)d_in[2];
    const float* b_ih_f = (const float*)d_in[3];
    const float* b_hh_f = (const float*)d_in[4];
    const float* w_ih_b = (const float*)d_in[5];
    // d_in[6] = w_hh_b — unused (backward cell starts from zero state)
    const float* b_ih_b = (const float*)d_in[7];
    const float* b_hh_b = (const float*)d_in[8];
    const float* w_fc   = (const float*)d_in[9];
    const float* b_fc   = (const float*)d_in[10];
    float* out = (float*)d_out;

    const int B = out_size;                 // 512
    const int T = in_sizes[0] / (B * 4);    // 1000

    bilstm_kernel<<<dim3(B / 2), dim3(256), 0, stream>>>(
        x, w_ih_f, w_hh_f, b_ih_f, b_hh_f,
        w_ih_b, b_ih_b, b_hh_b, w_fc, b_fc, out, T);
}